// Round 1
// baseline (303.789 us; speedup 1.0000x reference)
//
#include <hip/hip_runtime.h>
#include <math.h>

// Problem constants (LightRNN decoder): B*T = 2048 tokens, d = 768, table = 256
#define TABLE 256
#define DIM   768

// -log_softmax(logits)[target] where each of the 256 threads holds one logit.
__device__ __forceinline__ float block_nll(float logit, int target, float* red, int c) {
    // 1) max-reduce
    red[c] = logit;
    __syncthreads();
    #pragma unroll
    for (int s = 128; s > 0; s >>= 1) {
        if (c < s) red[c] = fmaxf(red[c], red[c + s]);
        __syncthreads();
    }
    float m = red[0];
    __syncthreads();
    // 2) sum of exp
    red[c] = __expf(logit - m) * 0.0f + expf(logit - m);  // use precise expf
    __syncthreads();
    #pragma unroll
    for (int s = 128; s > 0; s >>= 1) {
        if (c < s) red[c] += red[c + s];
        __syncthreads();
    }
    float lse = m + logf(red[0]);
    __syncthreads();
    // 3) fetch logit[target]
    if (c == target) red[0] = logit;
    __syncthreads();
    float lt = red[0];
    __syncthreads();
    return lse - lt;
}

__global__ __launch_bounds__(256) void lightrnn_fused_loss(
    const float* __restrict__ hs,     // (NTOK, DIM)
    const int*   __restrict__ tgt,    // (NTOK) int32
    const float* __restrict__ Wrow,   // (TABLE, DIM)
    const float* __restrict__ brow,   // (TABLE)
    const float* __restrict__ CW,     // (TABLE, DIM, TABLE)
    const float* __restrict__ cbias,  // (TABLE, TABLE)
    float* __restrict__ per_tok)      // (NTOK) workspace
{
    __shared__ float hs_s[DIM];
    __shared__ float red[256];

    const int n = blockIdx.x;
    const int c = threadIdx.x;

    const int t      = tgt[n];
    const int row_id = t >> 8;    // t / 256
    const int col_id = t & 255;   // t % 256

    // Stage this token's hidden state into LDS (768 f32 = 3 KB), vectorized.
    const float4* hs4   = reinterpret_cast<const float4*>(hs + (size_t)n * DIM);
    float4*       hs_s4 = reinterpret_cast<float4*>(hs_s);
    for (int i = c; i < DIM / 4; i += 256) hs_s4[i] = hs4[i];
    __syncthreads();

    // ---- row head: logit[c] = dot(hs, Wrow[c]) + brow[c] ----
    const float4* w4 = reinterpret_cast<const float4*>(Wrow + (size_t)c * DIM);
    float acc = 0.f;
    #pragma unroll 4
    for (int i = 0; i < DIM / 4; ++i) {
        float4 w = w4[i];
        float4 h = hs_s4[i];
        acc += w.x * h.x + w.y * h.y + w.z * h.z + w.w * h.w;
    }
    const float logit_row = acc + brow[c];
    const float loss_row  = block_nll(logit_row, row_id, red, c);

    // ---- col head: logit[c] = sum_d hs[d] * CW[row_id][d][c] + cbias[row_id][c] ----
    const float* wc = CW + (size_t)row_id * DIM * TABLE + c;
    float acc2 = 0.f;
    #pragma unroll 8
    for (int d = 0; d < DIM; ++d) {
        acc2 = fmaf(hs_s[d], wc[(size_t)d * TABLE], acc2);
    }
    const float logit_col = acc2 + cbias[(size_t)row_id * TABLE + c];
    const float loss_col  = block_nll(logit_col, col_id, red, c);

    if (c == 0) per_tok[n] = loss_row + loss_col;
}

__global__ __launch_bounds__(256) void lightrnn_reduce(
    const float* __restrict__ per_tok, int ntok, float* __restrict__ out)
{
    __shared__ float red[256];
    const int c = threadIdx.x;
    float s = 0.f;
    for (int i = c; i < ntok; i += 256) s += per_tok[i];
    red[c] = s;
    __syncthreads();
    #pragma unroll
    for (int k = 128; k > 0; k >>= 1) {
        if (c < k) red[c] += red[c + k];
        __syncthreads();
    }
    if (c == 0) out[0] = red[0] / (float)ntok;
}

extern "C" void kernel_launch(void* const* d_in, const int* in_sizes, int n_in,
                              void* d_out, int out_size, void* d_ws, size_t ws_size,
                              hipStream_t stream) {
    const float* hs    = (const float*)d_in[0];
    const int*   tgt   = (const int*)d_in[1];   // jnp.int64 under default JAX x64-off -> int32
    const float* Wrow  = (const float*)d_in[2];
    const float* brow  = (const float*)d_in[3];
    const float* CW    = (const float*)d_in[4];
    const float* cbias = (const float*)d_in[5];
    float* out = (float*)d_out;

    const int ntok = in_sizes[1];               // B*T = 2048
    float* per_tok = (float*)d_ws;              // ntok floats

    lightrnn_fused_loss<<<ntok, 256, 0, stream>>>(hs, tgt, Wrow, brow, CW, cbias, per_tok);
    lightrnn_reduce<<<1, 256, 0, stream>>>(per_tok, ntok, out);
}

// Round 2
// 76.291 us; speedup vs baseline: 3.9820x; 3.9820x over previous
//
#include <hip/hip_runtime.h>
#include <math.h>

#define TABLE 256
#define DIM   768
#define CAP   512          // bucket capacity per row (real max ~30 for Poisson(8))
#define NTOK_MAX 2048

// ---------------- float4 helpers ----------------
__device__ __forceinline__ float4 f4zero() { return make_float4(0.f, 0.f, 0.f, 0.f); }

// ---------------- kernel 1: zero counts + transpose Wrow ----------------
// grid 768 (one block per d), 256 threads (one per column c)
__global__ __launch_bounds__(256) void k_ztrans(
    const float* __restrict__ Wrow,   // (256, 768)
    float* __restrict__ WrowT,        // (768, 256)
    int* __restrict__ counts)         // (256)
{
    const int d = blockIdx.x;
    const int c = threadIdx.x;
    if (d == 0) counts[c] = 0;
    WrowT[(size_t)d * TABLE + c] = Wrow[(size_t)c * DIM + d];
}

// ---------------- kernel 2: bucket tokens by row id ----------------
__global__ __launch_bounds__(256) void k_bucket(
    const int* __restrict__ tgt, int ntok,
    int* __restrict__ counts, int* __restrict__ bucket)
{
    const int n = blockIdx.x * 256 + threadIdx.x;
    if (n >= ntok) return;
    const int r = tgt[n] >> 8;
    const int pos = atomicAdd(&counts[r], 1);
    if (pos < CAP) bucket[r * CAP + pos] = n;
}

// ---------------- grouped GEMM body ----------------
// Block: 256 threads. c4 = tid&31 (32 col-quads = 128 cols), dp = tid>>5 (8-way d-split).
// Computes out[toks[k]][cbase..cbase+127] = hs[toks[k]] . slab[:, cbase..] + bias.
template<int K>
__device__ __forceinline__ void gemm_body(
    const float4* __restrict__ slab4,   // (768, 64) float4  (d-major, 256 cols)
    const float*  __restrict__ hs,      // (NTOK, 768)
    const int* __restrict__ toks_s,     // LDS, K valid entries (>=kmax zero-filled)
    int kmax,
    float (*hs_s)[DIM],                 // LDS [16][768]
    float4 (*red)[4][32],               // LDS [4][4][32] float4
    const float4* __restrict__ bias4,   // (64) float4 for this row
    int cbase,
    float* __restrict__ outp,           // (NTOK, 256)
    int tid)
{
    const int c4 = tid & 31;
    const int dp = tid >> 5;

    // stage hs for the chunk (zero-fill unused k)
    for (int idx = tid; idx < K * (DIM / 4); idx += 256) {
        const int k = idx / (DIM / 4);
        const int i = idx - k * (DIM / 4);
        float4 v = f4zero();
        if (k < kmax)
            v = reinterpret_cast<const float4*>(hs + (size_t)toks_s[k] * DIM)[i];
        reinterpret_cast<float4*>(hs_s[k])[i] = v;
    }
    __syncthreads();

    float4 acc[K];
    #pragma unroll
    for (int k = 0; k < K; ++k) acc[k] = f4zero();

    const int cq = (cbase >> 2) + c4;
    #pragma unroll 4
    for (int d = dp; d < DIM; d += 8) {
        const float4 w = slab4[(size_t)d * (TABLE / 4) + cq];
        #pragma unroll
        for (int k = 0; k < K; ++k) {
            const float h = hs_s[k][d];
            acc[k].x = fmaf(h, w.x, acc[k].x);
            acc[k].y = fmaf(h, w.y, acc[k].y);
            acc[k].z = fmaf(h, w.z, acc[k].z);
            acc[k].w = fmaf(h, w.w, acc[k].w);
        }
    }

    // fold dp pairs within each wave (dp and dp+1 are lanes c4 / c4+32)
    #pragma unroll
    for (int k = 0; k < K; ++k) {
        acc[k].x += __shfl_xor(acc[k].x, 32);
        acc[k].y += __shfl_xor(acc[k].y, 32);
        acc[k].z += __shfl_xor(acc[k].z, 32);
        acc[k].w += __shfl_xor(acc[k].w, 32);
    }

    const int w    = tid >> 6;   // wave id 0..3
    const int lane = tid & 63;
    constexpr int KB = (K + 3) / 4;
    for (int kb = 0; kb < KB; ++kb) {
        if (lane < 32) {
            #pragma unroll
            for (int kk = 0; kk < 4; ++kk) {
                const int k = kb * 4 + kk;
                if (k < K) red[kk][w][lane] = acc[k];
            }
        }
        __syncthreads();
        if (tid < 128) {
            const int kk = tid >> 5;
            const int cc = tid & 31;
            const int k = kb * 4 + kk;
            if (k < K && k < kmax) {
                const float4 v0 = red[kk][0][cc];
                const float4 v1 = red[kk][1][cc];
                const float4 v2 = red[kk][2][cc];
                const float4 v3 = red[kk][3][cc];
                const float4 b  = bias4[(cbase >> 2) + cc];
                float4 o;
                o.x = v0.x + v1.x + v2.x + v3.x + b.x;
                o.y = v0.y + v1.y + v2.y + v3.y + b.y;
                o.z = v0.z + v1.z + v2.z + v3.z + b.z;
                o.w = v0.w + v1.w + v2.w + v3.w + b.w;
                reinterpret_cast<float4*>(outp + (size_t)toks_s[k] * TABLE + cbase)[cc] = o;
            }
        }
        __syncthreads();
    }
}

// ---------------- kernel 3: both GEMMs ----------------
// blocks [0,512): col head — (row r = bid>>1, col-half = bid&1), token list from bucket
// blocks [512,512+2*ntok/16): row head — 16-token tiles vs WrowT
__global__ __launch_bounds__(256) void k_gemms(
    const float* __restrict__ hs,
    const float* __restrict__ WrowT,
    const float* __restrict__ brow,
    const float* __restrict__ CW,
    const float* __restrict__ cbias,
    const int* __restrict__ counts,
    const int* __restrict__ bucket,
    float* __restrict__ row_logits,
    float* __restrict__ col_logits)
{
    __shared__ float  hs_s[16][DIM];
    __shared__ float4 red[4][4][32];
    __shared__ int    toks_s[16];

    const int bid = blockIdx.x;
    const int tid = threadIdx.x;

    if (bid < 512) {
        const int r = bid >> 1;
        const int cbase = (bid & 1) * 128;
        const int cnt = min(counts[r], CAP);
        if (cnt == 0) return;
        const float4* slab4 = reinterpret_cast<const float4*>(CW + (size_t)r * DIM * TABLE);
        const float4* bias4 = reinterpret_cast<const float4*>(cbias + (size_t)r * TABLE);
        for (int base = 0; base < cnt; base += 16) {
            const int kmax = min(16, cnt - base);
            if (tid < 16) toks_s[tid] = (tid < kmax) ? bucket[r * CAP + base + tid] : 0;
            __syncthreads();
            if (kmax <= 4)
                gemm_body<4>(slab4, hs, toks_s, kmax, hs_s, red, bias4, cbase, col_logits, tid);
            else if (kmax <= 8)
                gemm_body<8>(slab4, hs, toks_s, kmax, hs_s, red, bias4, cbase, col_logits, tid);
            else
                gemm_body<16>(slab4, hs, toks_s, kmax, hs_s, red, bias4, cbase, col_logits, tid);
        }
    } else {
        const int b = bid - 512;
        const int tile = b >> 1;
        const int cbase = (b & 1) * 128;
        if (tid < 16) toks_s[tid] = tile * 16 + tid;
        __syncthreads();
        const float4* slab4 = reinterpret_cast<const float4*>(WrowT);
        const float4* bias4 = reinterpret_cast<const float4*>(brow);
        gemm_body<16>(slab4, hs, toks_s, 16, hs_s, red, bias4, cbase, row_logits, tid);
    }
}

// ---------------- kernel 4: wave-parallel NLL per token ----------------
__device__ __forceinline__ float wave_nll(float4 v, int target, int lane) {
    float m = fmaxf(fmaxf(v.x, v.y), fmaxf(v.z, v.w));
    #pragma unroll
    for (int off = 32; off > 0; off >>= 1) m = fmaxf(m, __shfl_xor(m, off));
    float e = expf(v.x - m) + expf(v.y - m) + expf(v.z - m) + expf(v.w - m);
    float lt = 0.f;
    if (lane == (target >> 2)) {
        const int j = target & 3;
        lt = (j == 0) ? v.x : (j == 1) ? v.y : (j == 2) ? v.z : v.w;
    }
    #pragma unroll
    for (int off = 32; off > 0; off >>= 1) {
        e  += __shfl_xor(e, off);
        lt += __shfl_xor(lt, off);
    }
    return m + logf(e) - lt;
}

__global__ __launch_bounds__(256) void k_nll(
    const float* __restrict__ row_logits,
    const float* __restrict__ col_logits,
    const int* __restrict__ tgt, int ntok,
    float* __restrict__ per_tok)
{
    const int n = blockIdx.x * 4 + (threadIdx.x >> 6);
    if (n >= ntok) return;
    const int lane = threadIdx.x & 63;
    const int t = tgt[n];
    const float4 rl = reinterpret_cast<const float4*>(row_logits + (size_t)n * TABLE)[lane];
    const float4 cl = reinterpret_cast<const float4*>(col_logits + (size_t)n * TABLE)[lane];
    const float lr = wave_nll(rl, t >> 8, lane);
    const float lc = wave_nll(cl, t & 255, lane);
    if (lane == 0) per_tok[n] = lr + lc;
}

// ---------------- kernel 5: mean reduce ----------------
__global__ __launch_bounds__(256) void k_reduce(
    const float* __restrict__ per_tok, int ntok, float* __restrict__ out)
{
    __shared__ float red[256];
    const int c = threadIdx.x;
    float s = 0.f;
    for (int i = c; i < ntok; i += 256) s += per_tok[i];
    red[c] = s;
    __syncthreads();
    #pragma unroll
    for (int k = 128; k > 0; k >>= 1) {
        if (c < k) red[c] += red[c + k];
        __syncthreads();
    }
    if (c == 0) out[0] = red[0] / (float)ntok;
}

extern "C" void kernel_launch(void* const* d_in, const int* in_sizes, int n_in,
                              void* d_out, int out_size, void* d_ws, size_t ws_size,
                              hipStream_t stream) {
    const float* hs    = (const float*)d_in[0];
    const int*   tgt   = (const int*)d_in[1];
    const float* Wrow  = (const float*)d_in[2];
    const float* brow  = (const float*)d_in[3];
    const float* CW    = (const float*)d_in[4];
    const float* cbias = (const float*)d_in[5];
    float* out = (float*)d_out;

    const int ntok = in_sizes[1];   // 2048

    // workspace layout (bytes)
    char* ws = (char*)d_ws;
    int*   counts     = (int*)(ws);                               // 1 KB
    int*   bucket     = (int*)(ws + 1024);                        // 256*CAP*4 = 512 KB
    float* WrowT      = (float*)(ws + 1024 + 256 * CAP * 4);      // 768*256*4 = 768 KB
    float* row_logits = (float*)((char*)WrowT + DIM * TABLE * 4); // ntok*256*4 = 2 MB
    float* col_logits = row_logits + (size_t)ntok * TABLE;        // 2 MB
    float* per_tok    = col_logits + (size_t)ntok * TABLE;        // 8 KB

    k_ztrans <<<DIM, 256, 0, stream>>>(Wrow, WrowT, counts);
    k_bucket <<<(ntok + 255) / 256, 256, 0, stream>>>(tgt, ntok, counts, bucket);
    const int row_blocks = 2 * (ntok / 16);
    k_gemms  <<<512 + row_blocks, 256, 0, stream>>>(hs, WrowT, brow, CW, cbias,
                                                    counts, bucket, row_logits, col_logits);
    k_nll    <<<(ntok + 3) / 4, 256, 0, stream>>>(row_logits, col_logits, tgt, ntok, per_tok);
    k_reduce <<<1, 256, 0, stream>>>(per_tok, ntok, out);
}